// Round 1
// baseline (9791.434 us; speedup 1.0000x reference)
//
#include <hip/hip_runtime.h>
#include <hip/hip_bf16.h>
#include <stdint.h>

// Teacher-forced LSTM, B=64 T=512 D=H=1024.
// gates = m.(h@Wx^T) + (1-m).(x@Wx^T) + h@Wh^T + bx + bh   (blend moved to epilogue)
// Persistent kernel: 128 blocks x 512 thr; block owns 8 hidden units (32 gate rows).
// Weights bf16 [32][2048] (Wx|Wh) stationary in LDS, XOR-swizzled. h double-buffered
// (bf16) in ws; one atomic grid barrier per step; c in registers.

#define B_ 64
#define T_ 512
#define D_ 1024
#define H_ 1024
#define NBLK 128
#define UPB 8
#define NROW 32
#define NTHR 512

typedef __attribute__((ext_vector_type(8))) short short8;
typedef __attribute__((ext_vector_type(4))) float f32x4;

// LDS layout (bytes):
//   [0,131072)        W: 32 rows x 2048 bf16, byte(r,k) = (r*4096 + k*2) ^ ((r&7)<<4)
//   [131072,147968)   gbuf: float[2][64][33]  (K-half partial gates, padded stride)
//   [147968,148224)   m_lds: float[64]
//   [148224,148352)   bias_lds: float[32]
#define SMEM_BYTES 148352
#define GBUF_OFF 131072
#define MLDS_OFF 147968
#define BIAS_OFF 148224

__device__ __forceinline__ unsigned f2bf(float f) {          // fp32 -> bf16 RNE
  unsigned u = __float_as_uint(f);
  return (u + 0x7FFFu + ((u >> 16) & 1u)) >> 16;
}
__device__ __forceinline__ float sigf(float x) { return 1.0f / (1.0f + __expf(-x)); }
__device__ __forceinline__ float tanhf_(float x) { return 1.0f - 2.0f / (__expf(2.0f * x) + 1.0f); }

__global__ void cvt_x_kernel(const float* __restrict__ x, unsigned short* __restrict__ xb, int n4) {
  int i = blockIdx.x * blockDim.x + threadIdx.x;
  if (i >= n4) return;
  float4 v = ((const float4*)x)[i];
  ushort4 r;
  r.x = (unsigned short)f2bf(v.x);
  r.y = (unsigned short)f2bf(v.y);
  r.z = (unsigned short)f2bf(v.z);
  r.w = (unsigned short)f2bf(v.w);
  ((ushort4*)xb)[i] = r;
}

template<int XB>
__global__ __launch_bounds__(NTHR, 1)
void lstm_persist(const float* __restrict__ xf,
                  const unsigned short* __restrict__ xb,
                  const float* __restrict__ tm,
                  const float* __restrict__ Wx, const float* __restrict__ bxp,
                  const float* __restrict__ Wh, const float* __restrict__ bhp,
                  float* __restrict__ out,
                  unsigned short* __restrict__ hbuf,
                  unsigned* __restrict__ bar)
{
  extern __shared__ char smem[];
  float* gbuf    = (float*)(smem + GBUF_OFF);
  float* m_lds   = (float*)(smem + MLDS_OFF);
  float* bias_lds= (float*)(smem + BIAS_OFF);

  const int tid = threadIdx.x;
  const int bid = blockIdx.x;

  // ---- weights -> LDS (bf16, swizzled), once ----
  for (int r = 0; r < NROW; ++r) {
    const int grow = (r >> 3) * H_ + bid * UPB + (r & 7);   // gate g=r>>3, unit u=r&7
    const int xr = (r & 7) << 4;
    float2 v = ((const float2*)(Wx + (size_t)grow * D_))[tid];
    unsigned pk = f2bf(v.x) | (f2bf(v.y) << 16);
    *(unsigned*)(smem + ((r * 4096 + tid * 4) ^ xr)) = pk;
    v = ((const float2*)(Wh + (size_t)grow * H_))[tid];
    pk = f2bf(v.x) | (f2bf(v.y) << 16);
    *(unsigned*)(smem + ((r * 4096 + 2048 + tid * 4) ^ xr)) = pk;
  }
  if (tid < NROW) {
    const int grow = (tid >> 3) * H_ + bid * UPB + (tid & 7);
    bias_lds[tid] = bxp[grow] + bhp[grow];
  }

  const int lane = tid & 63;
  const int wid  = tid >> 6;     // 0..7
  const int mt   = wid & 3;      // M-tile (16 batch rows)
  const int kh   = wid >> 2;     // K-half (512 each)
  const int l15  = lane & 15;
  const int kg   = lane >> 4;
  const int arow = mt * 16 + l15;        // A-operand batch row

  const int xr0 = (l15 & 7) << 4;        // same for rows l15 and l15+16
  const unsigned wb0 = (unsigned)(l15 * 4096);
  const unsigned wb1 = (unsigned)((16 + l15) * 4096);
  const int kb0 = kh * 1024 + kg * 16;   // starting k byte offset within row

  const int cb = tid >> 3;               // cell: batch
  const int cu = tid & 7;                // cell: unit within block
  float ccell = 0.0f;

  unsigned cur = 0;
  __syncthreads();

  for (int t = 0; t < T_; ++t) {
    if (tid < B_) m_lds[tid] = tm[tid * T_ + t];
    __syncthreads();

    const unsigned short* hp = hbuf + cur * (B_ * H_) + arow * H_ + kh * 512 + kg * 8;
    const unsigned short* xp = nullptr;
    const float* xpf = nullptr;
    if (XB) xp  = xb + ((size_t)arow * T_ + t) * D_ + kh * 512 + kg * 8;
    else    xpf = xf + ((size_t)arow * T_ + t) * D_ + kh * 512 + kg * 8;

    f32x4 aA0 = {0,0,0,0}, aA1 = {0,0,0,0}, aB0 = {0,0,0,0},
          aB1 = {0,0,0,0}, aC0 = {0,0,0,0}, aC1 = {0,0,0,0};

    int kcur = kb0;
#pragma unroll 4
    for (int it = 0; it < 16; ++it) {
      short8 ah = *(const short8*)hp;
      short8 ax;
      if (XB) {
        ax = *(const short8*)xp;
        xp += 32;
      } else {
        float4 x0 = *(const float4*)xpf;
        float4 x1 = *(const float4*)(xpf + 4);
        ax[0] = (short)f2bf(x0.x); ax[1] = (short)f2bf(x0.y);
        ax[2] = (short)f2bf(x0.z); ax[3] = (short)f2bf(x0.w);
        ax[4] = (short)f2bf(x1.x); ax[5] = (short)f2bf(x1.y);
        ax[6] = (short)f2bf(x1.z); ax[7] = (short)f2bf(x1.w);
        xpf += 32;
      }
      const unsigned ks = (unsigned)(kcur ^ xr0);
      short8 wx0 = *(const short8*)(smem + wb0 + ks);
      short8 wh0 = *(const short8*)(smem + wb0 + 2048 + ks);
      short8 wx1 = *(const short8*)(smem + wb1 + ks);
      short8 wh1 = *(const short8*)(smem + wb1 + 2048 + ks);
      aA0 = __builtin_amdgcn_mfma_f32_16x16x32_bf16(ah, wx0, aA0, 0, 0, 0);
      aB0 = __builtin_amdgcn_mfma_f32_16x16x32_bf16(ax, wx0, aB0, 0, 0, 0);
      aC0 = __builtin_amdgcn_mfma_f32_16x16x32_bf16(ah, wh0, aC0, 0, 0, 0);
      aA1 = __builtin_amdgcn_mfma_f32_16x16x32_bf16(ah, wx1, aA1, 0, 0, 0);
      aB1 = __builtin_amdgcn_mfma_f32_16x16x32_bf16(ax, wx1, aB1, 0, 0, 0);
      aC1 = __builtin_amdgcn_mfma_f32_16x16x32_bf16(ah, wh1, aC1, 0, 0, 0);
      hp += 32;
      kcur += 64;
    }

    // epilogue: blend + bias -> gbuf[kh]   (C layout: col=lane&15, row=(lane>>4)*4+e)
#pragma unroll
    for (int e = 0; e < 4; ++e) {
      const int br = mt * 16 + kg * 4 + e;
      const float mv = m_lds[br];
      float g0 = mv * aA0[e] + (1.0f - mv) * aB0[e] + aC0[e];
      float g1 = mv * aA1[e] + (1.0f - mv) * aB1[e] + aC1[e];
      if (kh == 0) { g0 += bias_lds[l15]; g1 += bias_lds[16 + l15]; }
      gbuf[(kh * 64 + br) * 33 + l15] = g0;
      gbuf[(kh * 64 + br) * 33 + 16 + l15] = g1;
    }
    __syncthreads();

    // cell: one (b,u) per thread
    {
      const float gi = gbuf[cb * 33 + cu]      + gbuf[(64 + cb) * 33 + cu];
      const float gf = gbuf[cb * 33 + 8 + cu]  + gbuf[(64 + cb) * 33 + 8 + cu];
      const float gg = gbuf[cb * 33 + 16 + cu] + gbuf[(64 + cb) * 33 + 16 + cu];
      const float go = gbuf[cb * 33 + 24 + cu] + gbuf[(64 + cb) * 33 + 24 + cu];
      const float iv = sigf(gi), fv = sigf(gf), gv = tanhf_(gg), ov = sigf(go);
      ccell = ccell * fv + iv * gv;
      const float hv = ov * tanhf_(ccell);
      const int hu = bid * UPB + cu;
      out[((size_t)cb * T_ + t) * H_ + hu] = hv;
      hbuf[(cur ^ 1u) * (B_ * H_) + cb * H_ + hu] = (unsigned short)f2bf(hv);
      if (t == T_ - 1) {
        out[(size_t)B_ * T_ * H_ + cb * H_ + hu] = hv;
        out[(size_t)B_ * T_ * H_ + (size_t)B_ * H_ + cb * H_ + hu] = ccell;
      }
    }

    // grid barrier (all 128 blocks co-resident: 148KB LDS -> 1 block/CU)
    __syncthreads();
    if (tid == 0) {
      __threadfence();
      atomicAdd(bar, 1u);
      const unsigned target = (unsigned)(t + 1) * NBLK;
      while (__hip_atomic_load(bar, __ATOMIC_ACQUIRE, __HIP_MEMORY_SCOPE_AGENT) < target) {
        __builtin_amdgcn_s_sleep(2);
      }
      __threadfence();
    }
    __syncthreads();
    cur ^= 1u;
  }
}

extern "C" void kernel_launch(void* const* d_in, const int* in_sizes, int n_in,
                              void* d_out, int out_size, void* d_ws, size_t ws_size,
                              hipStream_t stream) {
  const float* x  = (const float*)d_in[0];
  const float* tm = (const float*)d_in[1];
  const float* Wx = (const float*)d_in[2];
  const float* bx = (const float*)d_in[3];
  const float* Wh = (const float*)d_in[4];
  const float* bh = (const float*)d_in[5];
  float* out = (float*)d_out;
  char* ws = (char*)d_ws;

  // ws layout: [0,4) barrier | [4096, 4096+256KiB) h double buffer bf16 | [266240, ..) x bf16
  unsigned* bar = (unsigned*)ws;
  unsigned short* hbuf = (unsigned short*)(ws + 4096);
  unsigned short* xb   = (unsigned short*)(ws + 266240);
  const size_t need_xb = 266240ull + 2ull * B_ * T_ * D_;
  const bool use_xb = ws_size >= need_xb;

  hipMemsetAsync(ws, 0, 266240, stream);   // zero barrier + both h buffers
  if (use_xb) {
    const int n4 = (B_ * T_ * D_) / 4;
    cvt_x_kernel<<<dim3((n4 + 255) / 256), dim3(256), 0, stream>>>(x, xb, n4);
    lstm_persist<1><<<dim3(NBLK), dim3(NTHR), SMEM_BYTES, stream>>>(x, xb, tm, Wx, bx, Wh, bh, out, hbuf, bar);
  } else {
    lstm_persist<0><<<dim3(NBLK), dim3(NTHR), SMEM_BYTES, stream>>>(x, xb, tm, Wx, bx, Wh, bh, out, hbuf, bar);
  }
}